// Round 14
// baseline (937.847 us; speedup 1.0000x reference)
//
#include <hip/hip_runtime.h>
#include <math.h>

typedef long long i64;
typedef unsigned short u16;
typedef unsigned int u32;

#define DIMC 384
#define DIM3 1152
#define HC 48
#define HWN 4096

using bf16x8 = __attribute__((ext_vector_type(8))) short;
using f32x4 = __attribute__((ext_vector_type(4))) float;

__device__ __forceinline__ float bf2f(u16 u) { u32 x = ((u32)u) << 16; return __uint_as_float(x); }
__device__ __forceinline__ u16 f2bf(float f) {
  u32 u = __float_as_uint(f);
  u32 r = u + 0x7FFFu + ((u >> 16) & 1u);
  return (u16)(r >> 16);
}
__device__ __forceinline__ u16 to_bf16(float f) { return f2bf(f); }
__device__ __forceinline__ u16 to_bf16(u16 u) { return u; }
__device__ __forceinline__ float ld_as_f(const float* p) { return *p; }
__device__ __forceinline__ float ld_as_f(const u16* p) { return bf2f(*p); }

__device__ __forceinline__ void gld_lds16(const u16* g, u16* l) {
  __builtin_amdgcn_global_load_lds(
      (const __attribute__((address_space(1))) void*)g,
      (__attribute__((address_space(3))) void*)l, 16, 0, 0);
}

// ---------------- utility kernels ----------------

// fp32 [M rows, K cols, row-stride lds] -> bf16 [1024][1024], zero padded
__global__ void cvt_pad_kernel(const float* __restrict__ src, int lds, int M, int K,
                               u16* __restrict__ out) {
  int idx = blockIdx.x * 256 + threadIdx.x;  // 1024*1024
  int r = idx >> 10, k = idx & 1023;
  out[idx] = (r < M && k < K) ? f2bf(src[(i64)r * lds + k]) : (u16)0;
}

// per-pixel LayerNorm stats over C=384 channels ([b][c][p] layout), 4 px/thread
template <typename T>
__global__ void stats_kernel(const T* __restrict__ x, float* __restrict__ mu,
                             float* __restrict__ rs, int npix4) {
  int idx = blockIdx.x * 256 + threadIdx.x;
  if (idx >= npix4) return;
  int pg = idx * 4;
  int b = pg >> 12, p = pg & 4095;
  const T* xp = x + ((i64)b * DIMC) * HWN + p;
  float s0 = 0.f, s1 = 0.f, s2 = 0.f, s3 = 0.f;
  float q0 = 0.f, q1 = 0.f, q2 = 0.f, q3 = 0.f;
  for (int c = 0; c < DIMC; ++c) {
    const T* rp = xp + (i64)c * HWN;
    float v0 = ld_as_f(rp), v1 = ld_as_f(rp + 1), v2 = ld_as_f(rp + 2), v3 = ld_as_f(rp + 3);
    s0 += v0; s1 += v1; s2 += v2; s3 += v3;
    q0 += v0 * v0; q1 += v1 * v1; q2 += v2 * v2; q3 += v3 * v3;
  }
  const float inv = 1.f / DIMC;
  float4 m = make_float4(s0 * inv, s1 * inv, s2 * inv, s3 * inv);
  float4 r;
  r.x = rsqrtf(q0 * inv - m.x * m.x + 1e-5f);
  r.y = rsqrtf(q1 * inv - m.y * m.y + 1e-5f);
  r.z = rsqrtf(q2 * inv - m.z * m.z + 1e-5f);
  r.w = rsqrtf(q3 * inv - m.w * m.w + 1e-5f);
  *(float4*)(mu + (i64)pg) = m;
  *(float4*)(rs + (i64)pg) = r;
}

// LN apply + transpose [b][c][p] -> [n][384] bf16 (64x64 LDS tile)
template <typename T>
__global__ __launch_bounds__(256) void ln_t_kernel(
    const T* __restrict__ x, const float* __restrict__ mu, const float* __restrict__ rs,
    const float* __restrict__ g, const float* __restrict__ bb, u16* __restrict__ y) {
  __shared__ u16 tile[64][66];
  int p0 = blockIdx.x * 64, c0 = blockIdx.y * 64, b = blockIdx.z;
  int t = threadIdx.x;
  int tp = t & 63, tq = t >> 6;
  float m = mu[b * 4096 + p0 + tp], r = rs[b * 4096 + p0 + tp];
  const T* xp = x + (i64)b * DIMC * HWN + (i64)c0 * 4096 + p0;
#pragma unroll
  for (int i = 0; i < 16; ++i) {
    int c = tq + i * 4;
    float v = ld_as_f(xp + (i64)c * 4096 + tp);
    tile[c][tp] = f2bf((v - m) * r * g[c0 + c] + bb[c0 + c]);
  }
  __syncthreads();
#pragma unroll
  for (int i = 0; i < 16; ++i) {
    int p = tq + i * 4;
    y[((i64)b * 4096 + p0 + p) * 384 + c0 + tp] = tile[tp][p];
  }
}

// depthwise 3x3 pad1, [n][c] bf16 in -> bf16 out; 4 channels x 4 pixels per thread.
__global__ __launch_bounds__(256) void dw8_kernel(const u16* __restrict__ in, int ldin,
                                                  const float* __restrict__ w,
                                                  const float* __restrict__ bias,
                                                  u16* __restrict__ out, int ldo, int CH) {
  int t = threadIdx.x;
  int g = t & 31;
  int s = t >> 5;
  int c0 = (blockIdx.y * 32 + g) * 4;
  if (c0 >= ldo) return;
  i64 p0 = (i64)blockIdx.x * 32 + s * 4;
  i64 pb = p0 & ~4095LL;
  int sp = (int)(p0 & 4095);
  int y = sp >> 6, x0 = sp & 63;
  float wv[9][4];
  float acc[4][4];
#pragma unroll
  for (int cc = 0; cc < 4; ++cc) {
    bool val = (c0 + cc) < CH;
    float bv = val ? bias[c0 + cc] : 0.f;
#pragma unroll
    for (int i = 0; i < 4; ++i) acc[i][cc] = bv;
#pragma unroll
    for (int j = 0; j < 9; ++j) wv[j][cc] = val ? w[(c0 + cc) * 9 + j] : 0.f;
  }
#pragma unroll
  for (int dy = 0; dy < 3; ++dy) {
    int yy = y - 1 + dy;
    if ((unsigned)yy >= 64u) continue;
    float row[6][4];
#pragma unroll
    for (int dx = 0; dx < 6; ++dx) {
      int xx = x0 - 1 + dx;
      if ((unsigned)xx < 64u) {
        ushort4 v = *(const ushort4*)(in + (pb + yy * 64 + xx) * ldin + c0);
        row[dx][0] = bf2f(v.x); row[dx][1] = bf2f(v.y);
        row[dx][2] = bf2f(v.z); row[dx][3] = bf2f(v.w);
      } else {
        row[dx][0] = 0.f; row[dx][1] = 0.f; row[dx][2] = 0.f; row[dx][3] = 0.f;
      }
    }
#pragma unroll
    for (int i = 0; i < 4; ++i)
#pragma unroll
      for (int dx = 0; dx < 3; ++dx)
#pragma unroll
        for (int cc = 0; cc < 4; ++cc)
          acc[i][cc] += row[i + dx][cc] * wv[dy * 3 + dx][cc];
  }
#pragma unroll
  for (int i = 0; i < 4; ++i) {
    ushort4 o;
    o.x = (c0 + 0 < CH) ? f2bf(acc[i][0]) : (u16)0;
    o.y = (c0 + 1 < CH) ? f2bf(acc[i][1]) : (u16)0;
    o.z = (c0 + 2 < CH) ? f2bf(acc[i][2]) : (u16)0;
    o.w = (c0 + 3 < CH) ? f2bf(acc[i][3]) : (u16)0;
    *(ushort4*)(out + (p0 + i) * ldo + c0) = o;
  }
}

// fused: depthwise 3x3 on q (in regs, q in [n][384]) + W-axis l2n + spm mult -> QS bf16;
// plane ssq for q and k (k read from kv buffer).
__global__ __launch_bounds__(192) void dwqnorm_kernel(
    const u16* __restrict__ qraw, const float* __restrict__ w9,
    const float* __restrict__ bias, const float* __restrict__ spm,
    const u16* __restrict__ kv, u16* __restrict__ QS,
    float* __restrict__ qssq, float* __restrict__ kssq) {
  int y = blockIdx.x;
  int b = blockIdx.y;
  int c = blockIdx.z * 192 + threadIdx.x;
  float wv[9];
#pragma unroll
  for (int j = 0; j < 9; ++j) wv[j] = w9[c * 9 + j];
  float bv = bias[c];
  float acc[64];
#pragma unroll
  for (int i = 0; i < 64; ++i) acc[i] = bv;
  i64 rowbase = (i64)b * 4096;
#pragma unroll
  for (int dy = 0; dy < 3; ++dy) {
    int yy = y - 1 + dy;
    if ((unsigned)yy >= 64u) continue;
    const u16* rp = qraw + (rowbase + yy * 64) * 384 + c;
    float w0 = wv[dy * 3 + 0], w1 = wv[dy * 3 + 1], w2 = wv[dy * 3 + 2];
#pragma unroll
    for (int xi = 0; xi < 64; ++xi) {
      float v = bf2f(rp[(i64)xi * 384]);
      if (xi > 0) acc[xi - 1] += v * w2;
      acc[xi] += v * w1;
      if (xi < 63) acc[xi + 1] += v * w0;
    }
  }
  float qs = 0.f;
#pragma unroll
  for (int i = 0; i < 64; ++i) qs += acc[i] * acc[i];
  float rw = 1.f / fmaxf(sqrtf(qs), 1e-12f);
  float ps = 0.f;
  const float* sp = spm + (i64)(y * 64) * 384 + c;
  u16* qp = QS + (rowbase + y * 64) * 384 + c;
#pragma unroll
  for (int i = 0; i < 64; ++i) {
    float u = acc[i] * rw * sp[(i64)i * 384];
    qp[(i64)i * 384] = f2bf(u);
    ps += u * u;
  }
  atomicAdd(&qssq[b * 384 + c], ps);
  float ks = 0.f;
  const u16* kp = kv + (rowbase + y * 64) * 768 + c;
#pragma unroll
  for (int i = 0; i < 64; ++i) {
    float kvv = bf2f(kp[(i64)i * 768]);
    ks += kvv * kvv;
  }
  atomicAdd(&kssq[b * 384 + c], ks);
}

// l2-normalize rows of 64
__global__ void l2row_kernel(const float* __restrict__ in, float* __restrict__ out) {
  int r = blockIdx.x;
  int lane = threadIdx.x;
  float v = in[r * 64 + lane];
  float ss = v * v;
  for (int o = 32; o > 0; o >>= 1) ss += __shfl_xor(ss, o);
  float n = fmaxf(sqrtf(ss), 1e-12f);
  out[r * 64 + lane] = v / n;
}

// conv 3x3, 3 -> 384 channels, output [p][384]
__global__ void spm_kernel(const float* __restrict__ s, const float* __restrict__ w,
                           const float* __restrict__ bias, float* __restrict__ out) {
  int idx = blockIdx.x * 256 + threadIdx.x;
  int c = idx % 384, p = idx / 384;
  int xc = p & 63, yr = p >> 6;
  const float* wp = w + c * 27;
  float acc = bias[c];
  for (int ic = 0; ic < 3; ++ic)
    for (int dy = -1; dy <= 1; ++dy) {
      int yy = yr + dy; if ((unsigned)yy >= 64u) continue;
      for (int dx = -1; dx <= 1; ++dx) {
        int xx = xc + dx; if ((unsigned)xx >= 64u) continue;
        acc += s[ic * 4096 + yy * 64 + xx] * wp[ic * 9 + (dy + 1) * 3 + (dx + 1)];
      }
    }
  out[idx] = acc;
}

// attn partials: attnP[bh][ksp][48][48] = sum_n QS[n][qc] * K[n][kc]
__global__ __launch_bounds__(256) void attnS_kernel(const u16* __restrict__ QS,
                                                    const u16* __restrict__ kv,
                                                    float* __restrict__ attnP) {
  int ksp = blockIdx.x;
  int bh = blockIdx.y;
  int b = bh >> 3, h = bh & 7;
  __shared__ float qsm[64][49];
  __shared__ float ksm[64][49];
  int t = threadIdx.x, tc = t & 15, td = t >> 4;
  float acc[3][3] = {{0.f}};
  for (int sub = 0; sub < 4; ++sub) {
    i64 nb = (i64)b * 4096 + ksp * 256 + sub * 64;
    __syncthreads();
    for (int l = t; l < 4096; l += 256) {
      int row = l >> 6, cq = l & 63;
      if (cq < 48) {
        qsm[row][cq] = bf2f(QS[(nb + row) * 384 + h * 48 + cq]);
        ksm[row][cq] = bf2f(kv[(nb + row) * 768 + h * 48 + cq]);
      }
    }
    __syncthreads();
#pragma unroll 4
    for (int nn = 0; nn < 64; ++nn) {
      float a0 = qsm[nn][tc], a1 = qsm[nn][tc + 16], a2 = qsm[nn][tc + 32];
      float b0 = ksm[nn][td], b1 = ksm[nn][td + 16], b2 = ksm[nn][td + 32];
      acc[0][0] += a0 * b0; acc[0][1] += a0 * b1; acc[0][2] += a0 * b2;
      acc[1][0] += a1 * b0; acc[1][1] += a1 * b1; acc[1][2] += a1 * b2;
      acc[2][0] += a2 * b0; acc[2][1] += a2 * b1; acc[2][2] += a2 * b2;
    }
  }
  float* ap = attnP + ((i64)bh * 16 + ksp) * 2304;
#pragma unroll
  for (int i = 0; i < 3; ++i)
#pragma unroll
    for (int j = 0; j < 3; ++j)
      ap[(tc + 16 * i) * HC + (td + 16 * j)] = acc[i][j];
}

// blend: fold plane-l2n of q (row) and k (col) + temperature, relu/top-k softmax mix
__global__ void blend_kernel(const float* __restrict__ attnP, const float* __restrict__ qssq,
                             const float* __restrict__ kssq, const float* __restrict__ temp,
                             const float* __restrict__ wmix, const float* __restrict__ pa1,
                             const float* __restrict__ pa2, const float* __restrict__ pa3,
                             const float* __restrict__ pa4, float* __restrict__ comb) {
  int row = blockIdx.x * 4 + (threadIdx.x >> 6);
  int lane = threadIdx.x & 63;
  int bh = row / 48, cc = row - bh * 48;
  int b = bh >> 3, h = bh & 7;
  float a;
  if (lane < 48) {
    const float* pp = attnP + ((i64)bh * 16) * 2304 + cc * 48 + lane;
    float s = 0.f;
#pragma unroll
    for (int sp = 0; sp < 16; ++sp) s += pp[(i64)sp * 2304];
    float qn = 1.f / fmaxf(sqrtf(qssq[b * 384 + h * 48 + cc]), 1e-12f);
    float kn = 1.f / fmaxf(sqrtf(kssq[b * 384 + h * 48 + lane]), 1e-12f);
    a = s * qn * kn * temp[h];
  } else {
    a = -INFINITY;
  }
  int rank = 0;
  for (int j = 0; j < 48; ++j) {
    float aj = __shfl(a, j);
    rank += (aj > a) ? 1 : 0;
  }
  float w0 = wmix[0], w1 = wmix[1];
  float wm = fmaxf(w0, w1);
  float e0 = expf(w0 - wm), e1 = expf(w1 - wm);
  float ws0 = e0 / (e0 + e1), ws1 = e1 / (e0 + e1);
  float c1 = pa1[0], c2 = pa2[0], c3 = pa3[0], c4 = pa4[0];
  float outv = ws0 * (c1 + c2 + c3 + c4) * fmaxf(a, 0.f);
  const int kks[4] = {24, 32, 36, 38};
  const float cs[4] = {c1, c2, c3, c4};
#pragma unroll
  for (int q = 0; q < 4; ++q) {
    float mv = (lane < 48) ? ((rank < kks[q]) ? a : a * 1e-6f) : -INFINITY;
    float mx = mv;
    for (int o = 32; o > 0; o >>= 1) mx = fmaxf(mx, __shfl_xor(mx, o));
    float e = (lane < 48) ? expf(mv - mx) : 0.f;
    float s = e;
    for (int o = 32; o > 0; o >>= 1) s += __shfl_xor(s, o);
    outv += ws1 * cs[q] * (e / s);
  }
  if (lane < 48) comb[(i64)row * 48 + lane] = outv;
}

// attn_out[n][c] = sum_d comb[b,h,cc,d] * V[n][384+h*48+d]  (V in kv bf16) -> bf16
__global__ __launch_bounds__(384) void combv_kernel(const u16* __restrict__ kv,
                                                    const float* __restrict__ comb,
                                                    u16* __restrict__ AO) {
  __shared__ float Vs[4][8][49];
  i64 p0 = (i64)blockIdx.x * 4;
  int b = (int)(p0 >> 12);
  int t = threadIdx.x;
  int h = t / 48, cc = t - h * 48;
#pragma unroll
  for (int px = 0; px < 4; ++px)
    Vs[px][h][cc] = bf2f(kv[(p0 + px) * 768 + 384 + t]);
  __syncthreads();
  float cr[48];
  const float* cp = comb + ((i64)(b * 8 + h) * 48 + cc) * 48;
#pragma unroll
  for (int d = 0; d < 48; d += 4) {
    float4 v = *(const float4*)(cp + d);
    cr[d] = v.x; cr[d + 1] = v.y; cr[d + 2] = v.z; cr[d + 3] = v.w;
  }
#pragma unroll
  for (int px = 0; px < 4; ++px) {
    float s = 0.f;
#pragma unroll
    for (int d = 0; d < 48; ++d) s += cr[d] * Vs[px][h][d];
    AO[(p0 + px) * 384 + t] = f2bf(s);
  }
}

// mat-vec (precompute)
__global__ void matvec_kernel(const float* __restrict__ Wm, int ldw, int koff,
                              const float* __restrict__ v, const float* __restrict__ add,
                              float* __restrict__ out, int K) {
  int ro = blockIdx.x;
  int t = threadIdx.x;
  const float* wp = Wm + (i64)ro * ldw + koff;
  float s = 0.f;
  for (int k = t; k < K; k += 256) s += wp[k] * v[k];
  __shared__ float sred[256];
  sred[t] = s;
  __syncthreads();
  for (int o = 128; o > 0; o >>= 1) {
    if (t < o) sred[t] += sred[t + o];
    __syncthreads();
  }
  if (t == 0) out[ro] = sred[0] + (add ? add[ro] : 0.f);
}

// pack weight [M][ldw] (cols koff..koff+K) into MFMA fragment order (row-major src)
template <typename T>
__global__ void pack_w_kernel(const T* __restrict__ W, int ldw, int koff, int M, int K,
                              int KS, u16* __restrict__ out, int nfrag) {
  int tid = blockIdx.x * 256 + threadIdx.x;
  int lane = tid & 63;
  int idx = tid >> 6;
  if (idx >= nfrag * KS) return;
  int ks = idx % KS, fm = idx / KS;
  int row = fm * 16 + (lane & 15);
  int kb = ks * 32 + (lane >> 4) * 8;
  union { u16 us[8]; uint4 q; } u;
#pragma unroll
  for (int j = 0; j < 8; ++j) {
    int k = kb + j;
    u.us[j] = (row < M && k < K) ? to_bf16(W[(i64)row * ldw + koff + k]) : (u16)0;
  }
  *(uint4*)(out + (i64)idx * 512 + lane * 8) = u.q;
}

// pack TRANSPOSED weight: element (row, k) = src[(kbase + k) * ldk + row]
template <typename T>
__global__ void pack_wT_kernel(const T* __restrict__ src, int ldk, i64 kbase, int M, int K,
                               int KS, u16* __restrict__ out, int nfrag) {
  int tid = blockIdx.x * 256 + threadIdx.x;
  int lane = tid & 63;
  int idx = tid >> 6;
  if (idx >= nfrag * KS) return;
  int ks = idx % KS, fm = idx / KS;
  int row = fm * 16 + (lane & 15);
  int kb = ks * 32 + (lane >> 4) * 8;
  union { u16 us[8]; uint4 q; } u;
#pragma unroll
  for (int j = 0; j < 8; ++j) {
    int k = kb + j;
    u.us[j] = (row < M && k < K) ? to_bf16(src[(kbase + k) * (i64)ldk + row]) : (u16)0;
  }
  *(uint4*)(out + (i64)idx * 512 + lane * 8) = u.q;
}

// ---------------- MFMA GEMM: (NF*16)n x 128m tile, BK=32, NF*32 threads ----------------
// SWAP=true (epi 0/2): operandi swapped -> m contiguous per thread -> ushort4 stores to
//   Yh[n][ldo] (m < msplit) or Yh2[n][ld2] (m >= msplit, offset by msplit).
// SWAP=false: epi 1 (bias + fp32 Res [b][c][p] -> bf16 Yh), epi 3 (bias + bf16 Res -> fp32 Yf).
template <int NF, bool SWAP>
__global__ __launch_bounds__(NF * 32) void gemm_nk_kernel(
    const u16* __restrict__ A1, int lda1, int KS1, const u16* __restrict__ Wp1,
    const u16* __restrict__ A2, int lda2, int KS2, const u16* __restrict__ Wp2,
    int nfrag, const float* __restrict__ bias,
    const void* __restrict__ Res, float* __restrict__ Yf, u16* __restrict__ Yh,
    int ldo, int msplit, u16* __restrict__ Yh2, int ld2,
    int M, int epi) {
  __shared__ __align__(16) u16 Ls[2][NF + 8][512];
  int t = threadIdx.x, lane = t & 63, w = t >> 6;
  int wn = w >> 1, wm = w & 1;
  i64 n0 = (i64)blockIdx.x * (NF * 16);
  int mt = blockIdx.y;

  f32x4 acc[4][4];
#pragma unroll
  for (int i = 0; i < 4; ++i)
#pragma unroll
    for (int r = 0; r < 4; ++r) acc[i][r] = (f32x4){0.f, 0.f, 0.f, 0.f};

  auto stage = [&](int kt, int buf) {
    const u16* A; int lda; const u16* Wp; int KSc; int ks;
    if (kt < KS1) { A = A1; lda = lda1; Wp = Wp1; KSc = KS1; ks = kt; }
    else { A = A2; lda = lda2; Wp = Wp2; KSc = KS2; ks = kt - KS1; }
#pragma unroll
    for (int j = 0; j < 2; ++j) {
      int f = w * 2 + j;
      const u16* srcA = A + (n0 + f * 16 + (lane & 15)) * (i64)lda + ks * 32 + (lane >> 4) * 8;
      gld_lds16(srcA, &Ls[buf][f][0]);
    }
    if constexpr (NF == 8) {
#pragma unroll
      for (int j = 0; j < 2; ++j) {
        int f = w * 2 + j;
        int fmc = min(mt * 8 + f, nfrag - 1);
        gld_lds16(Wp + ((i64)fmc * KSc + ks) * 512 + lane * 8, &Ls[buf][NF + f][0]);
      }
    } else {
      int fmc = min(mt * 8 + w, nfrag - 1);
      gld_lds16(Wp + ((i64)fmc * KSc + ks) * 512 + lane * 8, &Ls[buf][NF + w][0]);
    }
  };

  int KT = KS1 + KS2;
  stage(0, 0);
  __syncthreads();
  int s = 0;
  for (int kt = 0; kt < KT; ++kt) {
    if (kt + 1 < KT) stage(kt + 1, s ^ 1);
    bf16x8 af[4], wf[4];
#pragma unroll
    for (int i = 0; i < 4; ++i) {
      af[i] = *reinterpret_cast<const bf16x8*>(&Ls[s][wn * 4 + i][lane * 8]);
      wf[i] = *reinterpret_cast<const bf16x8*>(&Ls[s][NF + wm * 4 + i][lane * 8]);
    }
#pragma unroll
    for (int i = 0; i < 4; ++i)
#pragma unroll
      for (int r = 0; r < 4; ++r) {
        if constexpr (SWAP)
          acc[i][r] = __builtin_amdgcn_mfma_f32_16x16x32_bf16(wf[r], af[i], acc[i][r], 0, 0, 0);
        else
          acc[i][r] = __builtin_amdgcn_mfma_f32_16x16x32_bf16(af[i], wf[r], acc[i][r], 0, 0, 0);
      }
    __syncthreads();
    s ^= 1;
  }

  if constexpr (SWAP) {
    // output: n = lane&15 (per n-frag i), m = 4 contiguous per thread (per m-frag r)
#pragma unroll
    for (int i = 0; i < 4; ++i) {
      i64 n = n0 + (wn * 4 + i) * 16 + (lane & 15);
#pragma unroll
      for (int r = 0; r < 4; ++r) {
        int m4 = mt * 128 + (wm * 4 + r) * 16 + ((lane >> 4) << 2);
        float4 bv = *(const float4*)(bias + m4);
        float v0 = acc[i][r][0] + bv.x;
        float v1 = acc[i][r][1] + bv.y;
        float v2 = acc[i][r][2] + bv.z;
        float v3 = acc[i][r][3] + bv.w;
        if (epi == 2) {
          float g0 = 0.5f * v0 * (1.f + erff(v0 * 0.70710678118f));
          float g1 = 0.5f * v1 * (1.f + erff(v1 * 0.70710678118f));
          float g2 = 0.5f * v2 * (1.f + erff(v2 * 0.70710678118f));
          float g3 = 0.5f * v3 * (1.f + erff(v3 * 0.70710678118f));
          v0 *= g0; v1 *= g1; v2 *= g2; v3 *= g3;
        }
        ushort4 o;
        o.x = f2bf(v0); o.y = f2bf(v1); o.z = f2bf(v2); o.w = f2bf(v3);
        u16* dst = (m4 < msplit) ? (Yh + n * (i64)ldo + m4)
                                 : (Yh2 + n * (i64)ld2 + (m4 - msplit));
        *(ushort4*)dst = o;
      }
    }
  } else {
#pragma unroll
    for (int i = 0; i < 4; ++i) {
      int nbase = (int)n0 + (wn * 4 + i) * 16 + ((lane >> 4) << 2);
#pragma unroll
      for (int r = 0; r < 4; ++r) {
        int m = mt * 128 + (wm * 4 + r) * 16 + (lane & 15);
        if (m < M) {
          float bv = bias[m];
          int b = nbase >> 12, p = nbase & 4095;
          i64 off = ((i64)b * DIMC + m) * 4096 + p;
          if (epi == 1) {
            float4 rv = *(const float4*)((const float*)Res + off);
            ushort4 o;
            o.x = f2bf(acc[i][r][0] + bv + rv.x);
            o.y = f2bf(acc[i][r][1] + bv + rv.y);
            o.z = f2bf(acc[i][r][2] + bv + rv.z);
            o.w = f2bf(acc[i][r][3] + bv + rv.w);
            *(ushort4*)(Yh + off) = o;
          } else {
            ushort4 rv = *(const ushort4*)((const u16*)Res + off);
            float4 o;
            o.x = acc[i][r][0] + bv + bf2f(rv.x);
            o.y = acc[i][r][1] + bv + bf2f(rv.y);
            o.z = acc[i][r][2] + bv + bf2f(rv.z);
            o.w = acc[i][r][3] + bv + bf2f(rv.w);
            *(float4*)(Yf + off) = o;
          }
        }
      }
    }
  }
}

// ---------------- standalone adj GEMM: fully specialized, single-purpose ----------------
// fbf[n][1024] = gelu(y)*y, y = adj1 @ x1d (KS=32) + W3 @ xn2 (KS=12) + b3. 256n x 128m,
// 512 threads (NF=16 structure), non-SWAP scalar epilogue. nfrag=64, M=1021.
__global__ __launch_bounds__(512) void gemm_adj_kernel(
    const u16* __restrict__ A1, const u16* __restrict__ Wp1,
    const u16* __restrict__ A2, const u16* __restrict__ Wp2,
    const float* __restrict__ bias, u16* __restrict__ Yh) {
  constexpr int KS1 = 32, KS2 = 12, LDA1 = 1024, LDA2 = 384, LDO = 1024, M = 1021;
  __shared__ __align__(16) u16 Ls[2][24][512];
  int t = threadIdx.x, lane = t & 63, w = t >> 6;
  int wn = w >> 1, wm = w & 1;
  i64 n0 = (i64)blockIdx.x * 256;
  int mt = blockIdx.y;

  f32x4 acc[4][4];
#pragma unroll
  for (int i = 0; i < 4; ++i)
#pragma unroll
    for (int r = 0; r < 4; ++r) acc[i][r] = (f32x4){0.f, 0.f, 0.f, 0.f};

  auto stage = [&](int kt, int buf) {
    const u16* A; int lda; const u16* Wp; int KSc; int ks;
    if (kt < KS1) { A = A1; lda = LDA1; Wp = Wp1; KSc = KS1; ks = kt; }
    else { A = A2; lda = LDA2; Wp = Wp2; KSc = KS2; ks = kt - KS1; }
#pragma unroll
    for (int j = 0; j < 2; ++j) {
      int f = w * 2 + j;
      const u16* srcA = A + (n0 + f * 16 + (lane & 15)) * (i64)lda + ks * 32 + (lane >> 4) * 8;
      gld_lds16(srcA, &Ls[buf][f][0]);
    }
    int fmc = mt * 8 + w;  // nfrag = 64, mt < 8, w < 8 -> always in range
    gld_lds16(Wp + ((i64)fmc * KSc + ks) * 512 + lane * 8, &Ls[buf][16 + w][0]);
  };

  constexpr int KT = KS1 + KS2;
  stage(0, 0);
  __syncthreads();
  int s = 0;
  for (int kt = 0; kt < KT; ++kt) {
    if (kt + 1 < KT) stage(kt + 1, s ^ 1);
    bf16x8 af[4], wf[4];
#pragma unroll
    for (int i = 0; i < 4; ++i) {
      af[i] = *reinterpret_cast<const bf16x8*>(&Ls[s][wn * 4 + i][lane * 8]);
      wf[i] = *reinterpret_cast<const bf16x8*>(&Ls[s][16 + wm * 4 + i][lane * 8]);
    }
#pragma unroll
    for (int i = 0; i < 4; ++i)
#pragma unroll
      for (int r = 0; r < 4; ++r)
        acc[i][r] = __builtin_amdgcn_mfma_f32_16x16x32_bf16(af[i], wf[r], acc[i][r], 0, 0, 0);
    __syncthreads();
    s ^= 1;
  }

#pragma unroll
  for (int i = 0; i < 4; ++i) {
    int nbase = (int)n0 + (wn * 4 + i) * 16 + ((lane >> 4) << 2);
#pragma unroll
    for (int r = 0; r < 4; ++r) {
      int m = mt * 128 + (wm * 4 + r) * 16 + (lane & 15);
      float bv = (m < M) ? bias[m] : 0.f;
#pragma unroll
      for (int ii = 0; ii < 4; ++ii) {
        float v = acc[i][r][ii] + bv;
        float gg = 0.5f * v * (1.f + erff(v * 0.70710678118f));
        v = gg * v;
        if (m >= M) v = 0.f;
        Yh[(i64)(nbase + ii) * LDO + m] = f2bf(v);
      }
    }
  }
}

// ---------------- launch ----------------

extern "C" void kernel_launch(void* const* d_in, const int* in_sizes, int n_in,
                              void* d_out, int out_size, void* d_ws, size_t ws_size,
                              hipStream_t stream) {
  (void)in_sizes; (void)n_in; (void)out_size;
  const float* x       = (const float*)d_in[0];
  const float* spf     = (const float*)d_in[1];
  const float* ln1_w   = (const float*)d_in[2];
  const float* ln1_b   = (const float*)d_in[3];
  const float* qkv_w   = (const float*)d_in[4];
  const float* qkv_b   = (const float*)d_in[5];
  const float* qkvdw_w = (const float*)d_in[6];
  const float* qkvdw_b = (const float*)d_in[7];
  const float* proj_w  = (const float*)d_in[8];
  const float* proj_b  = (const float*)d_in[9];
  const float* temp    = (const float*)d_in[10];
  const float* a1      = (const float*)d_in[11];
  const float* a2      = (const float*)d_in[12];
  const float* a3      = (const float*)d_in[13];
  const float* a4      = (const float*)d_in[14];
  const float* wmix    = (const float*)d_in[15];
  const float* pout_w  = (const float*)d_in[16];
  const float* pout_b  = (const float*)d_in[17];
  const float* ln2_w   = (const float*)d_in[18];
  const float* ln2_b   = (const float*)d_in[19];
  const float* pin_w   = (const float*)d_in[20];
  const float* pin_b   = (const float*)d_in[21];
  const float* dw_w    = (const float*)d_in[22];
  const float* dw_b    = (const float*)d_in[23];
  const float* lin_w   = (const float*)d_in[24];
  const float* lin_b   = (const float*)d_in[25];
  const float* adj_w   = (const float*)d_in[26];
  const float* adj_b   = (const float*)d_in[27];
  const float* fout_w  = (const float*)d_in[28];
  const float* fout_b  = (const float*)d_in[29];
  float* out = (float*)d_out;
  float* ws = (float*)d_ws;

  const i64 PLANE = (i64)DIMC * HWN;  // 1,572,864
  const i64 FIXED = 4543488;
  const i64 PER = 6342656;
  int C = 8;
  while (C > 1 && (size_t)(FIXED + PER * C) * 4 > ws_size) C >>= 1;
  if ((size_t)(FIXED + PER * C) * 4 > ws_size) return;  // ws too small -> visible failure
  int nch = 8 / C;

  float* SPM   = ws;                          // 1572864
  float* b2v   = SPM + 1572864;               // 1024
  float* b3v   = b2v + 1024;                  // 1024
  float* zbias = b3v + 1024;                  // 1024
  float* spfn  = zbias + 1024;                // 12288
  float* mu1   = spfn + 12288;                // 32768
  float* rs1   = mu1 + 32768;
  float* mu2   = rs1 + 32768;
  float* rs2   = mu2 + 32768;
  float* qssq  = rs2 + 32768;                 // 3072
  float* kssq  = qssq + 3072;                 // 3072
  float* packbase = kssq + 3072;
  u16* qkv_wp  = (u16*)packbase;              // 884736 u16
  u16* pout_wp = qkv_wp + 884736;             // 294912
  u16* pin_wp  = pout_wp + 294912;            // 786432
  u16* adj1_wp = pin_wp + 786432;             // 2097152
  u16* W3_wp   = adj1_wp + 2097152;           // 786432
  u16* fout_wp = W3_wp + 786432;              // 786432
  float* dyn   = packbase + 2818048;

  // chunk arenas (floats)
  float* attnP = dyn;                          // C*294912
  float* comb  = attnP + (i64)C * 294912;      // C*18432
  float* RA    = comb + (i64)C * 18432;        // C*786432  (Xbf/QS/AO/xn2 bf16)
  float* RD    = RA + (i64)C * 786432;         // C*786432  (xatt bf16)
  float* RB    = RD + (i64)C * 786432;         // C*2359296 (qraw+kvraw / x1 / fbf bf16)
  float* RC    = RB + (i64)C * 2359296;        // C*2097152 (kv / x1d bf16)

  // precompute temporaries (alias chunk arenas; dead before chunk loop starts)
  u16* linbf    = (u16*)dyn;                   // 1,048,576 u16
  u16* adjbf    = linbf + 1048576;             // 1,048,576
  u16* W2bf     = adjbf + 1048576;             // 393,216 ([1024][384])
  u16* W3bf     = W2bf + 393216;               // 393,216
  u16* pin2T_wp = W3bf + 393216;               // 393,216
  u16* W2T_wp   = pin2T_wp + 393216;           // 393,216

  // ---- precompute: folded weights via MFMA ----
  hipMemsetAsync(b2v, 0, 3 * 1024 * sizeof(float), stream);  // b2v, b3v, zbias
  matvec_kernel<<<dim3(1021), dim3(256), 0, stream>>>(lin_w, 1021, 0, pin_b + 1021, lin_b, b2v, 1021);
  matvec_kernel<<<dim3(1021), dim3(256), 0, stream>>>(adj_w, 2042, 1021, b2v, adj_b, b3v, 1021);
  cvt_pad_kernel<<<dim3(4096), dim3(256), 0, stream>>>(lin_w, 1021, 1021, 1021, linbf);
  cvt_pad_kernel<<<dim3(4096), dim3(256), 0, stream>>>(adj_w + 1021, 2042, 1021, 1021, adjbf);
  pack_wT_kernel<float><<<dim3(192), dim3(256), 0, stream>>>(pin_w, 384, 1021, 384, 1021, 32,
                                                             pin2T_wp, 24);
  // W2 = lin @ pin2  -> bf16 [1024][384]
  gemm_nk_kernel<8, true><<<dim3(8, 3), dim3(256), 0, stream>>>(
      linbf, 1024, 32, pin2T_wp, nullptr, 0, 0, nullptr, 24,
      zbias, nullptr, nullptr, W2bf, 384, 1 << 30, nullptr, 0, 384, 0);
  pack_wT_kernel<u16><<<dim3(192), dim3(256), 0, stream>>>(W2bf, 384, 0, 384, 1021, 32,
                                                           W2T_wp, 24);
  // W3 = adj2 @ W2  -> bf16 [1024][384]
  gemm_nk_kernel<8, true><<<dim3(8, 3), dim3(256), 0, stream>>>(
      adjbf, 1024, 32, W2T_wp, nullptr, 0, 0, nullptr, 24,
      zbias, nullptr, nullptr, W3bf, 384, 1 << 30, nullptr, 0, 384, 0);
  pack_w_kernel<u16><<<dim3(192), dim3(256), 0, stream>>>(W3bf, 384, 0, 1021, 384, 12, W3_wp, 64);

  // ---- pack weights to MFMA fragment layout (bf16) ----
  pack_w_kernel<float><<<dim3(216), dim3(256), 0, stream>>>(qkv_w, 384, 0, 1152, 384, 12, qkv_wp, 72);
  pack_w_kernel<float><<<dim3(72), dim3(256), 0, stream>>>(pout_w, 384, 0, 384, 384, 12, pout_wp, 24);
  pack_w_kernel<float><<<dim3(192), dim3(256), 0, stream>>>(pin_w, 384, 0, 1021, 384, 12, pin_wp, 64);
  pack_w_kernel<float><<<dim3(512), dim3(256), 0, stream>>>(adj_w, 2042, 0, 1021, 1021, 32, adj1_wp, 64);
  pack_w_kernel<float><<<dim3(192), dim3(256), 0, stream>>>(fout_w, 1021, 0, 384, 1021, 32, fout_wp, 24);

  // ---- shared precompute ----
  l2row_kernel<<<dim3(192), dim3(64), 0, stream>>>(spf, spfn);
  spm_kernel<<<dim3(6144), dim3(256), 0, stream>>>(spfn, proj_w, proj_b, SPM);
  stats_kernel<float><<<dim3(32), dim3(256), 0, stream>>>(x, mu1, rs1, 8192);

  for (int ch = 0; ch < nch; ++ch) {
    int b0 = ch * C;
    const float* xb = x + (i64)b0 * PLANE;
    float* outb = out + (i64)b0 * PLANE;
    const float* m1 = mu1 + (i64)b0 * HWN;
    const float* r1 = rs1 + (i64)b0 * HWN;

    i64 NTOT = (i64)C * 4096;
    u16* Xbf   = (u16*)RA;                 // [n][384]
    u16* qraw  = (u16*)RB;                 // [n][384] (q pre-dw)
    u16* kvraw = qraw + NTOT * 384;        // [n][768] (k,v pre-dw)
    u16* kvb   = (u16*)RC;                 // [n][768] (k,v post-dw)
    u16* QS    = (u16*)RA;                 // (Xbf dead)
    u16* AO    = (u16*)RA;                 // (QS dead)
    u16* xatt  = (u16*)RD;                 // [b][c][p] bf16
    u16* xn2   = (u16*)RA;                 // (AO dead)
    u16* x1    = (u16*)RB;                 // [n][1024] (qraw/kvraw dead)
    u16* x1d   = (u16*)RC;                 // [n][1024] (kvb dead)
    u16* fbf   = (u16*)RB;                 // [n][1024] (x1 dead)

    int NB16 = C * 16;

    // ---- attention ----
    hipMemsetAsync(qssq, 0, 2 * 3072 * sizeof(float), stream);
    ln_t_kernel<float><<<dim3(64, 6, C), dim3(256), 0, stream>>>(xb, m1, r1, ln1_w, ln1_b, Xbf);
    gemm_nk_kernel<16, true><<<dim3(NB16, 9), dim3(512), 0, stream>>>(
        Xbf, 384, 12, qkv_wp, nullptr, 0, 0, nullptr, 72,
        qkv_b, nullptr, nullptr, qraw, 384, 384, kvraw, 768, 1152, 0);
    dw8_kernel<<<dim3(C * 128, 6), dim3(256), 0, stream>>>(
        kvraw, 768, qkvdw_w + 384 * 9, qkvdw_b + 384, kvb, 768, 768);
    dwqnorm_kernel<<<dim3(64, C, 2), dim3(192), 0, stream>>>(
        qraw, qkvdw_w, qkvdw_b, SPM, kvb, QS, qssq, kssq);
    attnS_kernel<<<dim3(16, C * 8), dim3(256), 0, stream>>>(QS, kvb, attnP);
    blend_kernel<<<dim3(96 * C), dim3(256), 0, stream>>>(attnP, qssq, kssq, temp, wmix,
                                                         a1, a2, a3, a4, comb);
    combv_kernel<<<dim3(C * 1024), dim3(384), 0, stream>>>(kvb, comb, AO);
    gemm_nk_kernel<16, false><<<dim3(NB16, 3), dim3(512), 0, stream>>>(
        AO, 384, 12, pout_wp, nullptr, 0, 0, nullptr, 24,
        pout_b, xb, nullptr, xatt, 0, 1 << 30, nullptr, 0, 384, 1);

    // ---- feed-forward ----
    stats_kernel<u16><<<dim3((C * 1024 + 255) / 256), dim3(256), 0, stream>>>(xatt, mu2, rs2,
                                                                              C * 1024);
    ln_t_kernel<u16><<<dim3(64, 6, C), dim3(256), 0, stream>>>(xatt, mu2, rs2, ln2_w, ln2_b, xn2);
    gemm_nk_kernel<16, true><<<dim3(NB16, 8), dim3(512), 0, stream>>>(
        xn2, 384, 12, pin_wp, nullptr, 0, 0, nullptr, 64,
        pin_b, nullptr, nullptr, x1, 1024, 1 << 30, nullptr, 0, 1021, 0);
    dw8_kernel<<<dim3(C * 128, 8), dim3(256), 0, stream>>>(
        x1, 1024, dw_w, dw_b, x1d, 1024, 1021);
    gemm_adj_kernel<<<dim3(NB16, 8), dim3(512), 0, stream>>>(
        x1d, adj1_wp, xn2, W3_wp, b3v, fbf);
    gemm_nk_kernel<16, false><<<dim3(NB16, 3), dim3(512), 0, stream>>>(
        fbf, 1024, 32, fout_wp, nullptr, 0, 0, nullptr, 24,
        fout_b, xatt, outb, nullptr, 0, 1 << 30, nullptr, 0, 384, 3);
  }
}

// Round 15
// 893.803 us; speedup vs baseline: 1.0493x; 1.0493x over previous
//
#include <hip/hip_runtime.h>
#include <math.h>

typedef long long i64;
typedef unsigned short u16;
typedef unsigned int u32;

#define DIMC 384
#define DIM3 1152
#define HC 48
#define HWN 4096

using bf16x8 = __attribute__((ext_vector_type(8))) short;
using f32x4 = __attribute__((ext_vector_type(4))) float;

__device__ __forceinline__ float bf2f(u16 u) { u32 x = ((u32)u) << 16; return __uint_as_float(x); }
__device__ __forceinline__ u16 f2bf(float f) {
  u32 u = __float_as_uint(f);
  u32 r = u + 0x7FFFu + ((u >> 16) & 1u);
  return (u16)(r >> 16);
}
__device__ __forceinline__ u16 to_bf16(float f) { return f2bf(f); }
__device__ __forceinline__ u16 to_bf16(u16 u) { return u; }
__device__ __forceinline__ float ld_as_f(const float* p) { return *p; }
__device__ __forceinline__ float ld_as_f(const u16* p) { return bf2f(*p); }

__device__ __forceinline__ void gld_lds16(const u16* g, u16* l) {
  __builtin_amdgcn_global_load_lds(
      (const __attribute__((address_space(1))) void*)g,
      (__attribute__((address_space(3))) void*)l, 16, 0, 0);
}

// ---------------- utility kernels ----------------

// fp32 [M rows, K cols, row-stride lds] -> bf16 [1024][1024], zero padded
__global__ void cvt_pad_kernel(const float* __restrict__ src, int lds, int M, int K,
                               u16* __restrict__ out) {
  int idx = blockIdx.x * 256 + threadIdx.x;  // 1024*1024
  int r = idx >> 10, k = idx & 1023;
  out[idx] = (r < M && k < K) ? f2bf(src[(i64)r * lds + k]) : (u16)0;
}

// per-pixel LayerNorm stats over C=384 channels ([b][c][p] layout), 4 px/thread
template <typename T>
__global__ void stats_kernel(const T* __restrict__ x, float* __restrict__ mu,
                             float* __restrict__ rs, int npix4) {
  int idx = blockIdx.x * 256 + threadIdx.x;
  if (idx >= npix4) return;
  int pg = idx * 4;
  int b = pg >> 12, p = pg & 4095;
  const T* xp = x + ((i64)b * DIMC) * HWN + p;
  float s0 = 0.f, s1 = 0.f, s2 = 0.f, s3 = 0.f;
  float q0 = 0.f, q1 = 0.f, q2 = 0.f, q3 = 0.f;
  for (int c = 0; c < DIMC; ++c) {
    const T* rp = xp + (i64)c * HWN;
    float v0 = ld_as_f(rp), v1 = ld_as_f(rp + 1), v2 = ld_as_f(rp + 2), v3 = ld_as_f(rp + 3);
    s0 += v0; s1 += v1; s2 += v2; s3 += v3;
    q0 += v0 * v0; q1 += v1 * v1; q2 += v2 * v2; q3 += v3 * v3;
  }
  const float inv = 1.f / DIMC;
  float4 m = make_float4(s0 * inv, s1 * inv, s2 * inv, s3 * inv);
  float4 r;
  r.x = rsqrtf(q0 * inv - m.x * m.x + 1e-5f);
  r.y = rsqrtf(q1 * inv - m.y * m.y + 1e-5f);
  r.z = rsqrtf(q2 * inv - m.z * m.z + 1e-5f);
  r.w = rsqrtf(q3 * inv - m.w * m.w + 1e-5f);
  *(float4*)(mu + (i64)pg) = m;
  *(float4*)(rs + (i64)pg) = r;
}

// LN apply + transpose [b][c][p] -> [n][384] bf16 (64x64 LDS tile)
template <typename T>
__global__ __launch_bounds__(256) void ln_t_kernel(
    const T* __restrict__ x, const float* __restrict__ mu, const float* __restrict__ rs,
    const float* __restrict__ g, const float* __restrict__ bb, u16* __restrict__ y) {
  __shared__ u16 tile[64][66];
  int p0 = blockIdx.x * 64, c0 = blockIdx.y * 64, b = blockIdx.z;
  int t = threadIdx.x;
  int tp = t & 63, tq = t >> 6;
  float m = mu[b * 4096 + p0 + tp], r = rs[b * 4096 + p0 + tp];
  const T* xp = x + (i64)b * DIMC * HWN + (i64)c0 * 4096 + p0;
#pragma unroll
  for (int i = 0; i < 16; ++i) {
    int c = tq + i * 4;
    float v = ld_as_f(xp + (i64)c * 4096 + tp);
    tile[c][tp] = f2bf((v - m) * r * g[c0 + c] + bb[c0 + c]);
  }
  __syncthreads();
#pragma unroll
  for (int i = 0; i < 16; ++i) {
    int p = tq + i * 4;
    y[((i64)b * 4096 + p0 + p) * 384 + c0 + tp] = tile[tp][p];
  }
}

// depthwise 3x3 pad1, [n][c] bf16 in -> bf16 out; 4 channels x 4 pixels per thread.
__global__ __launch_bounds__(256) void dw8_kernel(const u16* __restrict__ in, int ldin,
                                                  const float* __restrict__ w,
                                                  const float* __restrict__ bias,
                                                  u16* __restrict__ out, int ldo, int CH) {
  int t = threadIdx.x;
  int g = t & 31;
  int s = t >> 5;
  int c0 = (blockIdx.y * 32 + g) * 4;
  if (c0 >= ldo) return;
  i64 p0 = (i64)blockIdx.x * 32 + s * 4;
  i64 pb = p0 & ~4095LL;
  int sp = (int)(p0 & 4095);
  int y = sp >> 6, x0 = sp & 63;
  float wv[9][4];
  float acc[4][4];
#pragma unroll
  for (int cc = 0; cc < 4; ++cc) {
    bool val = (c0 + cc) < CH;
    float bv = val ? bias[c0 + cc] : 0.f;
#pragma unroll
    for (int i = 0; i < 4; ++i) acc[i][cc] = bv;
#pragma unroll
    for (int j = 0; j < 9; ++j) wv[j][cc] = val ? w[(c0 + cc) * 9 + j] : 0.f;
  }
#pragma unroll
  for (int dy = 0; dy < 3; ++dy) {
    int yy = y - 1 + dy;
    if ((unsigned)yy >= 64u) continue;
    float row[6][4];
#pragma unroll
    for (int dx = 0; dx < 6; ++dx) {
      int xx = x0 - 1 + dx;
      if ((unsigned)xx < 64u) {
        ushort4 v = *(const ushort4*)(in + (pb + yy * 64 + xx) * ldin + c0);
        row[dx][0] = bf2f(v.x); row[dx][1] = bf2f(v.y);
        row[dx][2] = bf2f(v.z); row[dx][3] = bf2f(v.w);
      } else {
        row[dx][0] = 0.f; row[dx][1] = 0.f; row[dx][2] = 0.f; row[dx][3] = 0.f;
      }
    }
#pragma unroll
    for (int i = 0; i < 4; ++i)
#pragma unroll
      for (int dx = 0; dx < 3; ++dx)
#pragma unroll
        for (int cc = 0; cc < 4; ++cc)
          acc[i][cc] += row[i + dx][cc] * wv[dy * 3 + dx][cc];
  }
#pragma unroll
  for (int i = 0; i < 4; ++i) {
    ushort4 o;
    o.x = (c0 + 0 < CH) ? f2bf(acc[i][0]) : (u16)0;
    o.y = (c0 + 1 < CH) ? f2bf(acc[i][1]) : (u16)0;
    o.z = (c0 + 2 < CH) ? f2bf(acc[i][2]) : (u16)0;
    o.w = (c0 + 3 < CH) ? f2bf(acc[i][3]) : (u16)0;
    *(ushort4*)(out + (p0 + i) * ldo + c0) = o;
  }
}

// fused: depthwise 3x3 on q (in regs, q in [n][384]) + W-axis l2n + spm mult -> QS bf16;
// plane ssq for q and k (k read from kv buffer).
__global__ __launch_bounds__(192) void dwqnorm_kernel(
    const u16* __restrict__ qraw, const float* __restrict__ w9,
    const float* __restrict__ bias, const float* __restrict__ spm,
    const u16* __restrict__ kv, u16* __restrict__ QS,
    float* __restrict__ qssq, float* __restrict__ kssq) {
  int y = blockIdx.x;
  int b = blockIdx.y;
  int c = blockIdx.z * 192 + threadIdx.x;
  float wv[9];
#pragma unroll
  for (int j = 0; j < 9; ++j) wv[j] = w9[c * 9 + j];
  float bv = bias[c];
  float acc[64];
#pragma unroll
  for (int i = 0; i < 64; ++i) acc[i] = bv;
  i64 rowbase = (i64)b * 4096;
#pragma unroll
  for (int dy = 0; dy < 3; ++dy) {
    int yy = y - 1 + dy;
    if ((unsigned)yy >= 64u) continue;
    const u16* rp = qraw + (rowbase + yy * 64) * 384 + c;
    float w0 = wv[dy * 3 + 0], w1 = wv[dy * 3 + 1], w2 = wv[dy * 3 + 2];
#pragma unroll
    for (int xi = 0; xi < 64; ++xi) {
      float v = bf2f(rp[(i64)xi * 384]);
      if (xi > 0) acc[xi - 1] += v * w2;
      acc[xi] += v * w1;
      if (xi < 63) acc[xi + 1] += v * w0;
    }
  }
  float qs = 0.f;
#pragma unroll
  for (int i = 0; i < 64; ++i) qs += acc[i] * acc[i];
  float rw = 1.f / fmaxf(sqrtf(qs), 1e-12f);
  float ps = 0.f;
  const float* sp = spm + (i64)(y * 64) * 384 + c;
  u16* qp = QS + (rowbase + y * 64) * 384 + c;
#pragma unroll
  for (int i = 0; i < 64; ++i) {
    float u = acc[i] * rw * sp[(i64)i * 384];
    qp[(i64)i * 384] = f2bf(u);
    ps += u * u;
  }
  atomicAdd(&qssq[b * 384 + c], ps);
  float ks = 0.f;
  const u16* kp = kv + (rowbase + y * 64) * 768 + c;
#pragma unroll
  for (int i = 0; i < 64; ++i) {
    float kvv = bf2f(kp[(i64)i * 768]);
    ks += kvv * kvv;
  }
  atomicAdd(&kssq[b * 384 + c], ks);
}

// l2-normalize rows of 64
__global__ void l2row_kernel(const float* __restrict__ in, float* __restrict__ out) {
  int r = blockIdx.x;
  int lane = threadIdx.x;
  float v = in[r * 64 + lane];
  float ss = v * v;
  for (int o = 32; o > 0; o >>= 1) ss += __shfl_xor(ss, o);
  float n = fmaxf(sqrtf(ss), 1e-12f);
  out[r * 64 + lane] = v / n;
}

// conv 3x3, 3 -> 384 channels, output [p][384]
__global__ void spm_kernel(const float* __restrict__ s, const float* __restrict__ w,
                           const float* __restrict__ bias, float* __restrict__ out) {
  int idx = blockIdx.x * 256 + threadIdx.x;
  int c = idx % 384, p = idx / 384;
  int xc = p & 63, yr = p >> 6;
  const float* wp = w + c * 27;
  float acc = bias[c];
  for (int ic = 0; ic < 3; ++ic)
    for (int dy = -1; dy <= 1; ++dy) {
      int yy = yr + dy; if ((unsigned)yy >= 64u) continue;
      for (int dx = -1; dx <= 1; ++dx) {
        int xx = xc + dx; if ((unsigned)xx >= 64u) continue;
        acc += s[ic * 4096 + yy * 64 + xx] * wp[ic * 9 + (dy + 1) * 3 + (dx + 1)];
      }
    }
  out[idx] = acc;
}

// attn partials: attnP[bh][ksp][48][48] = sum_n QS[n][qc] * K[n][kc]
__global__ __launch_bounds__(256) void attnS_kernel(const u16* __restrict__ QS,
                                                    const u16* __restrict__ kv,
                                                    float* __restrict__ attnP) {
  int ksp = blockIdx.x;
  int bh = blockIdx.y;
  int b = bh >> 3, h = bh & 7;
  __shared__ float qsm[64][49];
  __shared__ float ksm[64][49];
  int t = threadIdx.x, tc = t & 15, td = t >> 4;
  float acc[3][3] = {{0.f}};
  for (int sub = 0; sub < 4; ++sub) {
    i64 nb = (i64)b * 4096 + ksp * 256 + sub * 64;
    __syncthreads();
    for (int l = t; l < 4096; l += 256) {
      int row = l >> 6, cq = l & 63;
      if (cq < 48) {
        qsm[row][cq] = bf2f(QS[(nb + row) * 384 + h * 48 + cq]);
        ksm[row][cq] = bf2f(kv[(nb + row) * 768 + h * 48 + cq]);
      }
    }
    __syncthreads();
#pragma unroll 4
    for (int nn = 0; nn < 64; ++nn) {
      float a0 = qsm[nn][tc], a1 = qsm[nn][tc + 16], a2 = qsm[nn][tc + 32];
      float b0 = ksm[nn][td], b1 = ksm[nn][td + 16], b2 = ksm[nn][td + 32];
      acc[0][0] += a0 * b0; acc[0][1] += a0 * b1; acc[0][2] += a0 * b2;
      acc[1][0] += a1 * b0; acc[1][1] += a1 * b1; acc[1][2] += a1 * b2;
      acc[2][0] += a2 * b0; acc[2][1] += a2 * b1; acc[2][2] += a2 * b2;
    }
  }
  float* ap = attnP + ((i64)bh * 16 + ksp) * 2304;
#pragma unroll
  for (int i = 0; i < 3; ++i)
#pragma unroll
    for (int j = 0; j < 3; ++j)
      ap[(tc + 16 * i) * HC + (td + 16 * j)] = acc[i][j];
}

// blend: fold plane-l2n of q (row) and k (col) + temperature, relu/top-k softmax mix
__global__ void blend_kernel(const float* __restrict__ attnP, const float* __restrict__ qssq,
                             const float* __restrict__ kssq, const float* __restrict__ temp,
                             const float* __restrict__ wmix, const float* __restrict__ pa1,
                             const float* __restrict__ pa2, const float* __restrict__ pa3,
                             const float* __restrict__ pa4, float* __restrict__ comb) {
  int row = blockIdx.x * 4 + (threadIdx.x >> 6);
  int lane = threadIdx.x & 63;
  int bh = row / 48, cc = row - bh * 48;
  int b = bh >> 3, h = bh & 7;
  float a;
  if (lane < 48) {
    const float* pp = attnP + ((i64)bh * 16) * 2304 + cc * 48 + lane;
    float s = 0.f;
#pragma unroll
    for (int sp = 0; sp < 16; ++sp) s += pp[(i64)sp * 2304];
    float qn = 1.f / fmaxf(sqrtf(qssq[b * 384 + h * 48 + cc]), 1e-12f);
    float kn = 1.f / fmaxf(sqrtf(kssq[b * 384 + h * 48 + lane]), 1e-12f);
    a = s * qn * kn * temp[h];
  } else {
    a = -INFINITY;
  }
  int rank = 0;
  for (int j = 0; j < 48; ++j) {
    float aj = __shfl(a, j);
    rank += (aj > a) ? 1 : 0;
  }
  float w0 = wmix[0], w1 = wmix[1];
  float wm = fmaxf(w0, w1);
  float e0 = expf(w0 - wm), e1 = expf(w1 - wm);
  float ws0 = e0 / (e0 + e1), ws1 = e1 / (e0 + e1);
  float c1 = pa1[0], c2 = pa2[0], c3 = pa3[0], c4 = pa4[0];
  float outv = ws0 * (c1 + c2 + c3 + c4) * fmaxf(a, 0.f);
  const int kks[4] = {24, 32, 36, 38};
  const float cs[4] = {c1, c2, c3, c4};
#pragma unroll
  for (int q = 0; q < 4; ++q) {
    float mv = (lane < 48) ? ((rank < kks[q]) ? a : a * 1e-6f) : -INFINITY;
    float mx = mv;
    for (int o = 32; o > 0; o >>= 1) mx = fmaxf(mx, __shfl_xor(mx, o));
    float e = (lane < 48) ? expf(mv - mx) : 0.f;
    float s = e;
    for (int o = 32; o > 0; o >>= 1) s += __shfl_xor(s, o);
    outv += ws1 * cs[q] * (e / s);
  }
  if (lane < 48) comb[(i64)row * 48 + lane] = outv;
}

// attn_out[n][c] = sum_d comb[b,h,cc,d] * V[n][384+h*48+d]  (V in kv bf16) -> bf16
__global__ __launch_bounds__(384) void combv_kernel(const u16* __restrict__ kv,
                                                    const float* __restrict__ comb,
                                                    u16* __restrict__ AO) {
  __shared__ float Vs[4][8][49];
  i64 p0 = (i64)blockIdx.x * 4;
  int b = (int)(p0 >> 12);
  int t = threadIdx.x;
  int h = t / 48, cc = t - h * 48;
#pragma unroll
  for (int px = 0; px < 4; ++px)
    Vs[px][h][cc] = bf2f(kv[(p0 + px) * 768 + 384 + t]);
  __syncthreads();
  float cr[48];
  const float* cp = comb + ((i64)(b * 8 + h) * 48 + cc) * 48;
#pragma unroll
  for (int d = 0; d < 48; d += 4) {
    float4 v = *(const float4*)(cp + d);
    cr[d] = v.x; cr[d + 1] = v.y; cr[d + 2] = v.z; cr[d + 3] = v.w;
  }
#pragma unroll
  for (int px = 0; px < 4; ++px) {
    float s = 0.f;
#pragma unroll
    for (int d = 0; d < 48; ++d) s += cr[d] * Vs[px][h][d];
    AO[(p0 + px) * 384 + t] = f2bf(s);
  }
}

// mat-vec (precompute)
__global__ void matvec_kernel(const float* __restrict__ Wm, int ldw, int koff,
                              const float* __restrict__ v, const float* __restrict__ add,
                              float* __restrict__ out, int K) {
  int ro = blockIdx.x;
  int t = threadIdx.x;
  const float* wp = Wm + (i64)ro * ldw + koff;
  float s = 0.f;
  for (int k = t; k < K; k += 256) s += wp[k] * v[k];
  __shared__ float sred[256];
  sred[t] = s;
  __syncthreads();
  for (int o = 128; o > 0; o >>= 1) {
    if (t < o) sred[t] += sred[t + o];
    __syncthreads();
  }
  if (t == 0) out[ro] = sred[0] + (add ? add[ro] : 0.f);
}

// pack weight [M][ldw] (cols koff..koff+K) into MFMA fragment order (row-major src)
template <typename T>
__global__ void pack_w_kernel(const T* __restrict__ W, int ldw, int koff, int M, int K,
                              int KS, u16* __restrict__ out, int nfrag) {
  int tid = blockIdx.x * 256 + threadIdx.x;
  int lane = tid & 63;
  int idx = tid >> 6;
  if (idx >= nfrag * KS) return;
  int ks = idx % KS, fm = idx / KS;
  int row = fm * 16 + (lane & 15);
  int kb = ks * 32 + (lane >> 4) * 8;
  union { u16 us[8]; uint4 q; } u;
#pragma unroll
  for (int j = 0; j < 8; ++j) {
    int k = kb + j;
    u.us[j] = (row < M && k < K) ? to_bf16(W[(i64)row * ldw + koff + k]) : (u16)0;
  }
  *(uint4*)(out + (i64)idx * 512 + lane * 8) = u.q;
}

// pack TRANSPOSED weight: element (row, k) = src[(kbase + k) * ldk + row]
template <typename T>
__global__ void pack_wT_kernel(const T* __restrict__ src, int ldk, i64 kbase, int M, int K,
                               int KS, u16* __restrict__ out, int nfrag) {
  int tid = blockIdx.x * 256 + threadIdx.x;
  int lane = tid & 63;
  int idx = tid >> 6;
  if (idx >= nfrag * KS) return;
  int ks = idx % KS, fm = idx / KS;
  int row = fm * 16 + (lane & 15);
  int kb = ks * 32 + (lane >> 4) * 8;
  union { u16 us[8]; uint4 q; } u;
#pragma unroll
  for (int j = 0; j < 8; ++j) {
    int k = kb + j;
    u.us[j] = (row < M && k < K) ? to_bf16(src[(kbase + k) * (i64)ldk + row]) : (u16)0;
  }
  *(uint4*)(out + (i64)idx * 512 + lane * 8) = u.q;
}

// ---------------- MFMA GEMM: (NF*16)n x 128m tile, BK=32, NF*32 threads ----------------
// SWAP=true (epi 0/2): operandi swapped -> m contiguous per thread -> ushort4 stores to
//   Yh[n][ldo] (m < msplit) or Yh2[n][ld2] (m >= msplit, offset by msplit).
// SWAP=false: epi 1 (bias + fp32 Res [b][c][p] -> bf16 Yh), epi 3 (bias + bf16 Res -> fp32 Yf).
template <int NF, bool SWAP>
__global__ __launch_bounds__(NF * 32) void gemm_nk_kernel(
    const u16* __restrict__ A1, int lda1, int KS1, const u16* __restrict__ Wp1,
    const u16* __restrict__ A2, int lda2, int KS2, const u16* __restrict__ Wp2,
    int nfrag, const float* __restrict__ bias,
    const void* __restrict__ Res, float* __restrict__ Yf, u16* __restrict__ Yh,
    int ldo, int msplit, u16* __restrict__ Yh2, int ld2,
    int M, int epi) {
  __shared__ __align__(16) u16 Ls[2][NF + 8][512];
  int t = threadIdx.x, lane = t & 63, w = t >> 6;
  int wn = w >> 1, wm = w & 1;
  i64 n0 = (i64)blockIdx.x * (NF * 16);
  int mt = blockIdx.y;

  f32x4 acc[4][4];
#pragma unroll
  for (int i = 0; i < 4; ++i)
#pragma unroll
    for (int r = 0; r < 4; ++r) acc[i][r] = (f32x4){0.f, 0.f, 0.f, 0.f};

  auto stage = [&](int kt, int buf) {
    const u16* A; int lda; const u16* Wp; int KSc; int ks;
    if (kt < KS1) { A = A1; lda = lda1; Wp = Wp1; KSc = KS1; ks = kt; }
    else { A = A2; lda = lda2; Wp = Wp2; KSc = KS2; ks = kt - KS1; }
#pragma unroll
    for (int j = 0; j < 2; ++j) {
      int f = w * 2 + j;
      const u16* srcA = A + (n0 + f * 16 + (lane & 15)) * (i64)lda + ks * 32 + (lane >> 4) * 8;
      gld_lds16(srcA, &Ls[buf][f][0]);
    }
    if constexpr (NF == 8) {
#pragma unroll
      for (int j = 0; j < 2; ++j) {
        int f = w * 2 + j;
        int fmc = min(mt * 8 + f, nfrag - 1);
        gld_lds16(Wp + ((i64)fmc * KSc + ks) * 512 + lane * 8, &Ls[buf][NF + f][0]);
      }
    } else {
      int fmc = min(mt * 8 + w, nfrag - 1);
      gld_lds16(Wp + ((i64)fmc * KSc + ks) * 512 + lane * 8, &Ls[buf][NF + w][0]);
    }
  };

  int KT = KS1 + KS2;
  int s = 0;
  stage(0, 0);
  __syncthreads();

  for (int kt = 0; kt < KT; ++kt) {
    if (kt + 1 < KT) stage(kt + 1, s ^ 1);
    bf16x8 af[4], wf[4];
#pragma unroll
    for (int i = 0; i < 4; ++i) {
      af[i] = *reinterpret_cast<const bf16x8*>(&Ls[s][wn * 4 + i][lane * 8]);
      wf[i] = *reinterpret_cast<const bf16x8*>(&Ls[s][NF + wm * 4 + i][lane * 8]);
    }
#pragma unroll
    for (int i = 0; i < 4; ++i)
#pragma unroll
      for (int r = 0; r < 4; ++r) {
        if constexpr (SWAP)
          acc[i][r] = __builtin_amdgcn_mfma_f32_16x16x32_bf16(wf[r], af[i], acc[i][r], 0, 0, 0);
        else
          acc[i][r] = __builtin_amdgcn_mfma_f32_16x16x32_bf16(af[i], wf[r], acc[i][r], 0, 0, 0);
      }
    __syncthreads();
    s ^= 1;
  }

  if constexpr (SWAP) {
    // output: n = lane&15 (per n-frag i), m = 4 contiguous per thread (per m-frag r)
#pragma unroll
    for (int i = 0; i < 4; ++i) {
      i64 n = n0 + (wn * 4 + i) * 16 + (lane & 15);
#pragma unroll
      for (int r = 0; r < 4; ++r) {
        int m4 = mt * 128 + (wm * 4 + r) * 16 + ((lane >> 4) << 2);
        float4 bv = *(const float4*)(bias + m4);
        float v0 = acc[i][r][0] + bv.x;
        float v1 = acc[i][r][1] + bv.y;
        float v2 = acc[i][r][2] + bv.z;
        float v3 = acc[i][r][3] + bv.w;
        if (epi == 2) {
          float g0 = 0.5f * v0 * (1.f + erff(v0 * 0.70710678118f));
          float g1 = 0.5f * v1 * (1.f + erff(v1 * 0.70710678118f));
          float g2 = 0.5f * v2 * (1.f + erff(v2 * 0.70710678118f));
          float g3 = 0.5f * v3 * (1.f + erff(v3 * 0.70710678118f));
          v0 *= g0; v1 *= g1; v2 *= g2; v3 *= g3;
        }
        ushort4 o;
        o.x = f2bf(v0); o.y = f2bf(v1); o.z = f2bf(v2); o.w = f2bf(v3);
        u16* dst = (m4 < msplit) ? (Yh + n * (i64)ldo + m4)
                                 : (Yh2 + n * (i64)ld2 + (m4 - msplit));
        *(ushort4*)dst = o;
      }
    }
  } else {
#pragma unroll
    for (int i = 0; i < 4; ++i) {
      int nbase = (int)n0 + (wn * 4 + i) * 16 + ((lane >> 4) << 2);
#pragma unroll
      for (int r = 0; r < 4; ++r) {
        int m = mt * 128 + (wm * 4 + r) * 16 + (lane & 15);
        if (m < M) {
          float bv = bias[m];
          int b = nbase >> 12, p = nbase & 4095;
          i64 off = ((i64)b * DIMC + m) * 4096 + p;
          if (epi == 1) {
            float4 rv = *(const float4*)((const float*)Res + off);
            ushort4 o;
            o.x = f2bf(acc[i][r][0] + bv + rv.x);
            o.y = f2bf(acc[i][r][1] + bv + rv.y);
            o.z = f2bf(acc[i][r][2] + bv + rv.z);
            o.w = f2bf(acc[i][r][3] + bv + rv.w);
            *(ushort4*)(Yh + off) = o;
          } else {
            ushort4 rv = *(const ushort4*)((const u16*)Res + off);
            float4 o;
            o.x = acc[i][r][0] + bv + bf2f(rv.x);
            o.y = acc[i][r][1] + bv + bf2f(rv.y);
            o.z = acc[i][r][2] + bv + bf2f(rv.z);
            o.w = acc[i][r][3] + bv + bf2f(rv.w);
            *(float4*)(Yf + off) = o;
          }
        }
      }
    }
  }
}

// ---------------- launch ----------------

extern "C" void kernel_launch(void* const* d_in, const int* in_sizes, int n_in,
                              void* d_out, int out_size, void* d_ws, size_t ws_size,
                              hipStream_t stream) {
  (void)in_sizes; (void)n_in; (void)out_size;
  const float* x       = (const float*)d_in[0];
  const float* spf     = (const float*)d_in[1];
  const float* ln1_w   = (const float*)d_in[2];
  const float* ln1_b   = (const float*)d_in[3];
  const float* qkv_w   = (const float*)d_in[4];
  const float* qkv_b   = (const float*)d_in[5];
  const float* qkvdw_w = (const float*)d_in[6];
  const float* qkvdw_b = (const float*)d_in[7];
  const float* proj_w  = (const float*)d_in[8];
  const float* proj_b  = (const float*)d_in[9];
  const float* temp    = (const float*)d_in[10];
  const float* a1      = (const float*)d_in[11];
  const float* a2      = (const float*)d_in[12];
  const float* a3      = (const float*)d_in[13];
  const float* a4      = (const float*)d_in[14];
  const float* wmix    = (const float*)d_in[15];
  const float* pout_w  = (const float*)d_in[16];
  const float* pout_b  = (const float*)d_in[17];
  const float* ln2_w   = (const float*)d_in[18];
  const float* ln2_b   = (const float*)d_in[19];
  const float* pin_w   = (const float*)d_in[20];
  const float* pin_b   = (const float*)d_in[21];
  const float* dw_w    = (const float*)d_in[22];
  const float* dw_b    = (const float*)d_in[23];
  const float* lin_w   = (const float*)d_in[24];
  const float* lin_b   = (const float*)d_in[25];
  const float* adj_w   = (const float*)d_in[26];
  const float* adj_b   = (const float*)d_in[27];
  const float* fout_w  = (const float*)d_in[28];
  const float* fout_b  = (const float*)d_in[29];
  float* out = (float*)d_out;
  float* ws = (float*)d_ws;

  const i64 PLANE = (i64)DIMC * HWN;  // 1,572,864
  const i64 FIXED = 4543488;
  const i64 PER = 6342656;
  int C = 8;
  while (C > 1 && (size_t)(FIXED + PER * C) * 4 > ws_size) C >>= 1;
  if ((size_t)(FIXED + PER * C) * 4 > ws_size) return;  // ws too small -> visible failure
  int nch = 8 / C;

  float* SPM   = ws;                          // 1572864
  float* b2v   = SPM + 1572864;               // 1024
  float* b3v   = b2v + 1024;                  // 1024
  float* zbias = b3v + 1024;                  // 1024
  float* spfn  = zbias + 1024;                // 12288
  float* mu1   = spfn + 12288;                // 32768
  float* rs1   = mu1 + 32768;
  float* mu2   = rs1 + 32768;
  float* rs2   = mu2 + 32768;
  float* qssq  = rs2 + 32768;                 // 3072
  float* kssq  = qssq + 3072;                 // 3072
  float* packbase = kssq + 3072;
  u16* qkv_wp  = (u16*)packbase;              // 884736 u16
  u16* pout_wp = qkv_wp + 884736;             // 294912
  u16* pin_wp  = pout_wp + 294912;            // 786432
  u16* adj1_wp = pin_wp + 786432;             // 2097152
  u16* W3_wp   = adj1_wp + 2097152;           // 786432
  u16* fout_wp = W3_wp + 786432;              // 786432
  float* dyn   = packbase + 2818048;

  // chunk arenas (floats)
  float* attnP = dyn;                          // C*294912
  float* comb  = attnP + (i64)C * 294912;      // C*18432
  float* RA    = comb + (i64)C * 18432;        // C*786432  (Xbf/QS/AO/xn2 bf16)
  float* RD    = RA + (i64)C * 786432;         // C*786432  (xatt bf16)
  float* RB    = RD + (i64)C * 786432;         // C*2359296 (qraw+kvraw / x1 / fbf bf16)
  float* RC    = RB + (i64)C * 2359296;        // C*2097152 (kv / x1d bf16)

  // precompute temporaries (alias chunk arenas; dead before chunk loop starts)
  u16* linbf    = (u16*)dyn;                   // 1,048,576 u16
  u16* adjbf    = linbf + 1048576;             // 1,048,576
  u16* W2bf     = adjbf + 1048576;             // 393,216 ([1024][384])
  u16* W3bf     = W2bf + 393216;               // 393,216
  u16* pin2T_wp = W3bf + 393216;               // 393,216
  u16* W2T_wp   = pin2T_wp + 393216;           // 393,216

  // ---- precompute: folded weights via MFMA ----
  hipMemsetAsync(b2v, 0, 3 * 1024 * sizeof(float), stream);  // b2v, b3v, zbias
  matvec_kernel<<<dim3(1021), dim3(256), 0, stream>>>(lin_w, 1021, 0, pin_b + 1021, lin_b, b2v, 1021);
  matvec_kernel<<<dim3(1021), dim3(256), 0, stream>>>(adj_w, 2042, 1021, b2v, adj_b, b3v, 1021);
  cvt_pad_kernel<<<dim3(4096), dim3(256), 0, stream>>>(lin_w, 1021, 1021, 1021, linbf);
  cvt_pad_kernel<<<dim3(4096), dim3(256), 0, stream>>>(adj_w + 1021, 2042, 1021, 1021, adjbf);
  pack_wT_kernel<float><<<dim3(192), dim3(256), 0, stream>>>(pin_w, 384, 1021, 384, 1021, 32,
                                                             pin2T_wp, 24);
  // W2 = lin @ pin2  -> bf16 [1024][384]
  gemm_nk_kernel<8, true><<<dim3(8, 3), dim3(256), 0, stream>>>(
      linbf, 1024, 32, pin2T_wp, nullptr, 0, 0, nullptr, 24,
      zbias, nullptr, nullptr, W2bf, 384, 1 << 30, nullptr, 0, 384, 0);
  pack_wT_kernel<u16><<<dim3(192), dim3(256), 0, stream>>>(W2bf, 384, 0, 384, 1021, 32,
                                                           W2T_wp, 24);
  // W3 = adj2 @ W2  -> bf16 [1024][384]
  gemm_nk_kernel<8, true><<<dim3(8, 3), dim3(256), 0, stream>>>(
      adjbf, 1024, 32, W2T_wp, nullptr, 0, 0, nullptr, 24,
      zbias, nullptr, nullptr, W3bf, 384, 1 << 30, nullptr, 0, 384, 0);
  pack_w_kernel<u16><<<dim3(192), dim3(256), 0, stream>>>(W3bf, 384, 0, 1021, 384, 12, W3_wp, 64);

  // ---- pack weights to MFMA fragment layout (bf16) ----
  pack_w_kernel<float><<<dim3(216), dim3(256), 0, stream>>>(qkv_w, 384, 0, 1152, 384, 12, qkv_wp, 72);
  pack_w_kernel<float><<<dim3(72), dim3(256), 0, stream>>>(pout_w, 384, 0, 384, 384, 12, pout_wp, 24);
  pack_w_kernel<float><<<dim3(192), dim3(256), 0, stream>>>(pin_w, 384, 0, 1021, 384, 12, pin_wp, 64);
  pack_w_kernel<float><<<dim3(512), dim3(256), 0, stream>>>(adj_w, 2042, 0, 1021, 1021, 32, adj1_wp, 64);
  pack_w_kernel<float><<<dim3(192), dim3(256), 0, stream>>>(fout_w, 1021, 0, 384, 1021, 32, fout_wp, 24);

  // ---- shared precompute ----
  l2row_kernel<<<dim3(192), dim3(64), 0, stream>>>(spf, spfn);
  spm_kernel<<<dim3(6144), dim3(256), 0, stream>>>(spfn, proj_w, proj_b, SPM);
  stats_kernel<float><<<dim3(32), dim3(256), 0, stream>>>(x, mu1, rs1, 8192);

  for (int ch = 0; ch < nch; ++ch) {
    int b0 = ch * C;
    const float* xb = x + (i64)b0 * PLANE;
    float* outb = out + (i64)b0 * PLANE;
    const float* m1 = mu1 + (i64)b0 * HWN;
    const float* r1 = rs1 + (i64)b0 * HWN;

    i64 NTOT = (i64)C * 4096;
    u16* Xbf   = (u16*)RA;                 // [n][384]
    u16* qraw  = (u16*)RB;                 // [n][384] (q pre-dw)
    u16* kvraw = qraw + NTOT * 384;        // [n][768] (k,v pre-dw)
    u16* kvb   = (u16*)RC;                 // [n][768] (k,v post-dw)
    u16* QS    = (u16*)RA;                 // (Xbf dead)
    u16* AO    = (u16*)RA;                 // (QS dead)
    u16* xatt  = (u16*)RD;                 // [b][c][p] bf16
    u16* xn2   = (u16*)RA;                 // (AO dead)
    u16* x1    = (u16*)RB;                 // [n][1024] (qraw/kvraw dead)
    u16* x1d   = (u16*)RC;                 // [n][1024] (kv dead)
    u16* fbf   = (u16*)RB;                 // [n][1024] (x1 dead)

    int NB16 = C * 16;

    // ---- attention ----
    hipMemsetAsync(qssq, 0, 2 * 3072 * sizeof(float), stream);
    ln_t_kernel<float><<<dim3(64, 6, C), dim3(256), 0, stream>>>(xb, m1, r1, ln1_w, ln1_b, Xbf);
    gemm_nk_kernel<16, true><<<dim3(NB16, 9), dim3(512), 0, stream>>>(
        Xbf, 384, 12, qkv_wp, nullptr, 0, 0, nullptr, 72,
        qkv_b, nullptr, nullptr, qraw, 384, 384, kvraw, 768, 1152, 0);
    dw8_kernel<<<dim3(C * 128, 6), dim3(256), 0, stream>>>(
        kvraw, 768, qkvdw_w + 384 * 9, qkvdw_b + 384, kvb, 768, 768);
    dwqnorm_kernel<<<dim3(64, C, 2), dim3(192), 0, stream>>>(
        qraw, qkvdw_w, qkvdw_b, SPM, kvb, QS, qssq, kssq);
    attnS_kernel<<<dim3(16, C * 8), dim3(256), 0, stream>>>(QS, kvb, attnP);
    blend_kernel<<<dim3(96 * C), dim3(256), 0, stream>>>(attnP, qssq, kssq, temp, wmix,
                                                         a1, a2, a3, a4, comb);
    combv_kernel<<<dim3(C * 1024), dim3(384), 0, stream>>>(kvb, comb, AO);
    gemm_nk_kernel<16, false><<<dim3(NB16, 3), dim3(512), 0, stream>>>(
        AO, 384, 12, pout_wp, nullptr, 0, 0, nullptr, 24,
        pout_b, xb, nullptr, xatt, 0, 1 << 30, nullptr, 0, 384, 1);

    // ---- feed-forward ----
    stats_kernel<u16><<<dim3((C * 1024 + 255) / 256), dim3(256), 0, stream>>>(xatt, mu2, rs2,
                                                                              C * 1024);
    ln_t_kernel<u16><<<dim3(64, 6, C), dim3(256), 0, stream>>>(xatt, mu2, rs2, ln2_w, ln2_b, xn2);
    gemm_nk_kernel<16, true><<<dim3(NB16, 8), dim3(512), 0, stream>>>(
        xn2, 384, 12, pin_wp, nullptr, 0, 0, nullptr, 64,
        pin_b, nullptr, nullptr, x1, 1024, 1 << 30, nullptr, 0, 1021, 0);
    dw8_kernel<<<dim3(C * 128, 8), dim3(256), 0, stream>>>(
        x1, 1024, dw_w, dw_b, x1d, 1024, 1021);
    gemm_nk_kernel<16, true><<<dim3(NB16, 8), dim3(512), 0, stream>>>(
        x1d, 1024, 32, adj1_wp, xn2, 384, 12, W3_wp, 64,
        b3v, nullptr, nullptr, fbf, 1024, 1 << 30, nullptr, 0, 1021, 2);
    gemm_nk_kernel<16, false><<<dim3(NB16, 3), dim3(512), 0, stream>>>(
        fbf, 1024, 32, fout_wp, nullptr, 0, 0, nullptr, 24,
        fout_b, xatt, outb, nullptr, 0, 1 << 30, nullptr, 0, 384, 3);
  }
}